// Round 1
// baseline (2131.808 us; speedup 1.0000x reference)
//
#include <hip/hip_runtime.h>
#include <math.h>

#define NPTS 262144
#define CIN  72
#define DIM  256

typedef _Float16 h8v __attribute__((ext_vector_type(8)));
typedef _Float16 h4v __attribute__((ext_vector_type(4)));
typedef float    f4v __attribute__((ext_vector_type(4)));

__device__ __forceinline__ float gelu_erf(float x) {
    return 0.5f * x * (1.0f + erff(x * 0.70710678118654752440f));
}

// ---------------------------------------------------------------- prep ----
__global__ void prep_kernel(const float* __restrict__ w1, const float* __restrict__ w2,
                            const float* __restrict__ p1, const float* __restrict__ p2,
                            _Float16* __restrict__ WT1, _Float16* __restrict__ WT2,
                            _Float16* __restrict__ WTp1, _Float16* __restrict__ WTp2,
                            float* __restrict__ sumexp, float* __restrict__ pooled)
{
    int idx = blockIdx.x * 256 + threadIdx.x;
    if (idx < 24576) {                       // WT1[n][k] = ip_w1[k][n], k padded 72->96
        int n = idx / 96, k = idx - n * 96;
        WT1[idx] = (_Float16)(k < CIN ? w1[k * DIM + n] : 0.0f);
    } else if (idx < 24576 + 65536) {
        int t = idx - 24576; int n = t >> 8, k = t & 255;
        WT2[t] = (_Float16)w2[k * DIM + n];
    } else if (idx < 24576 + 131072) {
        int t = idx - (24576 + 65536); int n = t >> 8, k = t & 255;
        WTp1[t] = (_Float16)p1[k * DIM + n];
    } else if (idx < 24576 + 196608) {
        int t = idx - (24576 + 131072); int n = t >> 8, k = t & 255;
        WTp2[t] = (_Float16)p2[k * DIM + n];
    } else if (idx < 24576 + 196608 + 384) {
        sumexp[idx - (24576 + 196608)] = 0.0f;
    } else if (idx < 24576 + 196608 + 384 + 98304) {
        pooled[idx - (24576 + 196608 + 384)] = 0.0f;
    }
}

// ----------------------------------------------------------- block reduce --
__device__ __forceinline__ float block_sum256(float v, float* s4) {
    #pragma unroll
    for (int off = 1; off < 64; off <<= 1) v += __shfl_xor(v, off, 64);
    __syncthreads();
    if ((threadIdx.x & 63) == 0) s4[threadIdx.x >> 6] = v;
    __syncthreads();
    return s4[0] + s4[1] + s4[2] + s4[3];
}

// ---------------------------------------------------------------- query ----
__global__ __launch_bounds__(256) void query_kernel(
    const float* __restrict__ qe, const float* __restrict__ qg, const float* __restrict__ qb,
    const float* __restrict__ qw1, const float* __restrict__ qb1,
    const float* __restrict__ qw2, const float* __restrict__ qb2,
    float* __restrict__ qemb, _Float16* __restrict__ qmask)
{
    __shared__ float sv[DIM], s2[DIM], s4[4];
    const int row = blockIdx.x, g = row >> 7, d = threadIdx.x;
    const float* w1 = qw1 + (size_t)g * DIM * DIM;
    const float* w2 = qw2 + (size_t)g * DIM * DIM;
    float x = qe[row * DIM + d];
    float mean = block_sum256(x, s4) * (1.0f / DIM);
    float dv = x - mean;
    float var = block_sum256(dv * dv, s4) * (1.0f / DIM);
    float y = dv * rsqrtf(var + 1e-5f) * qg[g * DIM + d] + qb[g * DIM + d];
    sv[d] = y;
    __syncthreads();
    float a1 = 0.0f;
    for (int k = 0; k < DIM; ++k) a1 += sv[k] * w1[k * DIM + d];
    a1 = gelu_erf(a1 + qb1[g * DIM + d]);
    s2[d] = a1;
    __syncthreads();
    float a2 = 0.0f;
    for (int k = 0; k < DIM; ++k) a2 += s2[k] * w2[k * DIM + d];
    float q2 = x + a2 + qb2[g * DIM + d];
    qemb[row * DIM + d] = q2;
    float ss = block_sum256(q2 * q2, s4);
    float inv = 1.0f / fmaxf(sqrtf(ss), 1e-12f);
    qmask[row * DIM + d] = (_Float16)(q2 * inv);
}

// ----------------------------------------------------------- trunk GEMMs ---
__device__ __forceinline__ void zero_acc44(f4v (&acc)[4][4]) {
    #pragma unroll
    for (int m = 0; m < 4; ++m)
        #pragma unroll
        for (int n = 0; n < 4; ++n) {
            f4v z = {0.0f, 0.0f, 0.0f, 0.0f};
            acc[m][n] = z;
        }
}

__device__ __forceinline__ void mm_tile(f4v (&acc)[4][4], const _Float16* sA,
                                        const _Float16* __restrict__ WT, int wtStride,
                                        int nKt, int cb, int l15, int lg)
{
    for (int kt = 0; kt < nKt; ++kt) {
        h8v a[4], b[4];
        #pragma unroll
        for (int m = 0; m < 4; ++m)
            a[m] = *(const h8v*)(sA + (m * 16 + l15) * 264 + kt * 32 + lg * 8);
        #pragma unroll
        for (int n = 0; n < 4; ++n)
            b[n] = *(const h8v*)(WT + (size_t)(cb + n * 16 + l15) * wtStride + kt * 32 + lg * 8);
        #pragma unroll
        for (int m = 0; m < 4; ++m)
            #pragma unroll
            for (int n = 0; n < 4; ++n)
                acc[m][n] = __builtin_amdgcn_mfma_f32_16x16x32_f16(a[m], b[n], acc[m][n], 0, 0, 0);
    }
}

// per-row (mean, rstd) from acc (bias already added); results in sStat
__device__ __forceinline__ void ln_stats(const f4v (&acc)[4][4],
                                         float (*sRed)[64][2], float (*sStat)[2],
                                         int wv, int l15, int lg, int tid)
{
    #pragma unroll
    for (int m = 0; m < 4; ++m) {
        float s[4] = {0, 0, 0, 0}, ss[4] = {0, 0, 0, 0};
        #pragma unroll
        for (int n = 0; n < 4; ++n)
            #pragma unroll
            for (int i = 0; i < 4; ++i) { float v = acc[m][n][i]; s[i] += v; ss[i] += v * v; }
        #pragma unroll
        for (int off = 1; off < 16; off <<= 1)
            #pragma unroll
            for (int i = 0; i < 4; ++i) {
                s[i] += __shfl_xor(s[i], off, 64);
                ss[i] += __shfl_xor(ss[i], off, 64);
            }
        if (l15 == 0)
            #pragma unroll
            for (int i = 0; i < 4; ++i) {
                int r = m * 16 + lg * 4 + i;
                sRed[wv][r][0] = s[i]; sRed[wv][r][1] = ss[i];
            }
    }
    __syncthreads();
    if (tid < 64) {
        float s = 0, ss = 0;
        #pragma unroll
        for (int w = 0; w < 4; ++w) { s += sRed[w][tid][0]; ss += sRed[w][tid][1]; }
        float mean = s * (1.0f / 256.0f);
        float var = ss * (1.0f / 256.0f) - mean * mean;
        sStat[tid][0] = mean;
        sStat[tid][1] = rsqrtf(var + 1e-5f);
    }
    __syncthreads();
}

__global__ __launch_bounds__(256, 2) void trunk_kernel(
    const float* __restrict__ pf,
    const float* __restrict__ ib1, const float* __restrict__ ig, const float* __restrict__ ibb,
    const float* __restrict__ ib2,
    const float* __restrict__ pg, const float* __restrict__ pb,
    const float* __restrict__ pb1, const float* __restrict__ pb2,
    const _Float16* __restrict__ WT1, const _Float16* __restrict__ WT2,
    const _Float16* __restrict__ WTp1, const _Float16* __restrict__ WTp2,
    float* __restrict__ peo, float* __restrict__ inv_norm, _Float16* __restrict__ peT)
{
    __shared__ __align__(16) _Float16 sAct[64][264];
    __shared__ float sRed[4][64][2];
    __shared__ float sStat[64][2];

    const int tid = threadIdx.x;
    const int wv = tid >> 6, ln = tid & 63, l15 = ln & 15, lg = ln >> 4;
    const int cb = wv * 64;
    const int rowbase = blockIdx.x * 64;

    // stage point_feat (64x72 -> padded 96) as fp16
    for (int idx = tid; idx < 64 * 96; idx += 256) {
        int r = idx / 96, c = idx - r * 96;
        sAct[r][c] = (_Float16)(c < CIN ? pf[(size_t)(rowbase + r) * CIN + c] : 0.0f);
    }
    __syncthreads();

    f4v acc[4][4];
    float h4[4][4][4];

    // ---- GEMM1: pf @ ip_w1, +b1, LN, GELU -> act1
    zero_acc44(acc);
    mm_tile(acc, &sAct[0][0], WT1, 96, 3, cb, l15, lg);
    {
        float bc[4], gc[4], bb[4];
        #pragma unroll
        for (int n = 0; n < 4; ++n) {
            int col = cb + n * 16 + l15;
            bc[n] = ib1[col]; gc[n] = ig[col]; bb[n] = ibb[col];
        }
        #pragma unroll
        for (int m = 0; m < 4; ++m)
            #pragma unroll
            for (int n = 0; n < 4; ++n)
                #pragma unroll
                for (int i = 0; i < 4; ++i) acc[m][n][i] += bc[n];
        ln_stats(acc, sRed, sStat, wv, l15, lg, tid);
        #pragma unroll
        for (int m = 0; m < 4; ++m)
            #pragma unroll
            for (int i = 0; i < 4; ++i) {
                int r = m * 16 + lg * 4 + i;
                float mean = sStat[r][0], rstd = sStat[r][1];
                #pragma unroll
                for (int n = 0; n < 4; ++n) {
                    float v = (acc[m][n][i] - mean) * rstd * gc[n] + bb[n];
                    sAct[r][cb + n * 16 + l15] = (_Float16)gelu_erf(v);
                }
            }
    }
    __syncthreads();

    // ---- GEMM2: act1 @ ip_w2, +b2 = h ; act2 = LN(h)
    zero_acc44(acc);
    mm_tile(acc, &sAct[0][0], WT2, 256, 8, cb, l15, lg);
    {
        float bc[4], gc[4], bb[4];
        #pragma unroll
        for (int n = 0; n < 4; ++n) {
            int col = cb + n * 16 + l15;
            bc[n] = ib2[col]; gc[n] = pg[col]; bb[n] = pb[col];
        }
        #pragma unroll
        for (int m = 0; m < 4; ++m)
            #pragma unroll
            for (int n = 0; n < 4; ++n)
                #pragma unroll
                for (int i = 0; i < 4; ++i) {
                    float h = acc[m][n][i] + bc[n];
                    h4[m][n][i] = h;
                    acc[m][n][i] = h;
                }
        ln_stats(acc, sRed, sStat, wv, l15, lg, tid);
        #pragma unroll
        for (int m = 0; m < 4; ++m)
            #pragma unroll
            for (int i = 0; i < 4; ++i) {
                int r = m * 16 + lg * 4 + i;
                float mean = sStat[r][0], rstd = sStat[r][1];
                #pragma unroll
                for (int n = 0; n < 4; ++n) {
                    float v = (h4[m][n][i] - mean) * rstd * gc[n] + bb[n];
                    sAct[r][cb + n * 16 + l15] = (_Float16)v;   // no GELU here
                }
            }
    }
    __syncthreads();

    // ---- GEMM3: act2 @ ph_w1, +b, GELU -> act3
    zero_acc44(acc);
    mm_tile(acc, &sAct[0][0], WTp1, 256, 8, cb, l15, lg);
    __syncthreads();   // all reads of act2 complete before overwrite
    {
        float bc[4];
        #pragma unroll
        for (int n = 0; n < 4; ++n) bc[n] = pb1[cb + n * 16 + l15];
        #pragma unroll
        for (int m = 0; m < 4; ++m)
            #pragma unroll
            for (int i = 0; i < 4; ++i) {
                int r = m * 16 + lg * 4 + i;
                #pragma unroll
                for (int n = 0; n < 4; ++n) {
                    float v = gelu_erf(acc[m][n][i] + bc[n]);
                    sAct[r][cb + n * 16 + l15] = (_Float16)v;
                }
            }
    }
    __syncthreads();

    // ---- GEMM4: act3 @ ph_w2, +b, +h  -> point_embed
    zero_acc44(acc);
    mm_tile(acc, &sAct[0][0], WTp2, 256, 8, cb, l15, lg);
    {
        float bc[4];
        #pragma unroll
        for (int n = 0; n < 4; ++n) bc[n] = pb2[cb + n * 16 + l15];
        #pragma unroll
        for (int m = 0; m < 4; ++m)
            #pragma unroll
            for (int n = 0; n < 4; ++n)
                #pragma unroll
                for (int i = 0; i < 4; ++i)
                    acc[m][n][i] += bc[n] + h4[m][n][i];
        // row L2-norm
        #pragma unroll
        for (int m = 0; m < 4; ++m) {
            float ss[4] = {0, 0, 0, 0};
            #pragma unroll
            for (int n = 0; n < 4; ++n)
                #pragma unroll
                for (int i = 0; i < 4; ++i) { float v = acc[m][n][i]; ss[i] += v * v; }
            #pragma unroll
            for (int off = 1; off < 16; off <<= 1)
                #pragma unroll
                for (int i = 0; i < 4; ++i) ss[i] += __shfl_xor(ss[i], off, 64);
            if (l15 == 0)
                #pragma unroll
                for (int i = 0; i < 4; ++i) sRed[wv][m * 16 + lg * 4 + i][0] = ss[i];
        }
        __syncthreads();
        if (tid < 64) {
            float ss = 0;
            #pragma unroll
            for (int w = 0; w < 4; ++w) ss += sRed[w][tid][0];
            float inv = 1.0f / fmaxf(sqrtf(ss), 1e-12f);
            sStat[tid][0] = inv;
            inv_norm[rowbase + tid] = inv;
        }
        __syncthreads();
        // outputs: point_embed fp32 + peT fp16 (transposed)
        #pragma unroll
        for (int m = 0; m < 4; ++m)
            #pragma unroll
            for (int n = 0; n < 4; ++n) {
                int col = cb + n * 16 + l15;
                h4v pk;
                #pragma unroll
                for (int i = 0; i < 4; ++i) {
                    int r = m * 16 + lg * 4 + i;
                    float v = acc[m][n][i];
                    peo[(size_t)(rowbase + r) * DIM + col] = v;
                    pk[i] = (_Float16)v;
                }
                *(h4v*)(peT + (size_t)col * NPTS + rowbase + m * 16 + lg * 4) = pk;
            }
    }
}

// --------------------------------------------------------------- logits ----
__global__ __launch_bounds__(256, 2) void logits_kernel(
    const _Float16* __restrict__ qmask, const float* __restrict__ peo,
    const float* __restrict__ inv_norm, const float* __restrict__ lsc,
    float* __restrict__ ml, float* __restrict__ sumexp)
{
    const int tid = threadIdx.x;
    const int wv = tid >> 6, ln = tid & 63, l15 = ln & 15, lg = ln >> 4;
    const int nb = blockIdx.x * 64;
    const int mb = wv * 96;

    f4v acc[6][4];
    #pragma unroll
    for (int m = 0; m < 6; ++m)
        #pragma unroll
        for (int n = 0; n < 4; ++n) { f4v z = {0, 0, 0, 0}; acc[m][n] = z; }

    float inv[4];
    #pragma unroll
    for (int n = 0; n < 4; ++n) inv[n] = inv_norm[nb + n * 16 + l15];

    for (int kt = 0; kt < 8; ++kt) {
        h8v a[6], b[4];
        #pragma unroll
        for (int n = 0; n < 4; ++n) {
            const float* p = peo + (size_t)(nb + n * 16 + l15) * DIM + kt * 32 + lg * 8;
            float4 u0 = *(const float4*)p;
            float4 u1 = *(const float4*)(p + 4);
            h8v t;
            t[0] = (_Float16)(u0.x * inv[n]); t[1] = (_Float16)(u0.y * inv[n]);
            t[2] = (_Float16)(u0.z * inv[n]); t[3] = (_Float16)(u0.w * inv[n]);
            t[4] = (_Float16)(u1.x * inv[n]); t[5] = (_Float16)(u1.y * inv[n]);
            t[6] = (_Float16)(u1.z * inv[n]); t[7] = (_Float16)(u1.w * inv[n]);
            b[n] = t;
        }
        #pragma unroll
        for (int m = 0; m < 6; ++m)
            a[m] = *(const h8v*)(qmask + (size_t)(mb + m * 16 + l15) * DIM + kt * 32 + lg * 8);
        #pragma unroll
        for (int m = 0; m < 6; ++m)
            #pragma unroll
            for (int n = 0; n < 4; ++n)
                acc[m][n] = __builtin_amdgcn_mfma_f32_16x16x32_f16(a[m], b[n], acc[m][n], 0, 0, 0);
    }

    #pragma unroll
    for (int m = 0; m < 6; ++m) {
        int g = (mb + m * 16) >> 7;
        float sc = expf(lsc[g]);
        float es[4] = {0, 0, 0, 0};
        #pragma unroll
        for (int n = 0; n < 4; ++n)
            #pragma unroll
            for (int i = 0; i < 4; ++i) {
                int row = mb + m * 16 + lg * 4 + i;
                int col = nb + n * 16 + l15;
                float v = acc[m][n][i] * sc;
                ml[(size_t)row * NPTS + col] = v;
                es[i] += __expf(v);
            }
        #pragma unroll
        for (int off = 1; off < 16; off <<= 1)
            #pragma unroll
            for (int i = 0; i < 4; ++i) es[i] += __shfl_xor(es[i], off, 64);
        if (l15 == 0)
            #pragma unroll
            for (int i = 0; i < 4; ++i)
                atomicAdd(&sumexp[mb + m * 16 + lg * 4 + i], es[i]);
    }
}

// --------------------------------------------------------------- pooled ----
__global__ __launch_bounds__(512, 2) void pooled_kernel(
    const float* __restrict__ ml, const _Float16* __restrict__ peT,
    float* __restrict__ pooled)
{
    const int tid = threadIdx.x;
    const int wv = tid >> 6, ln = tid & 63, l15 = ln & 15, lg = ln >> 4;
    const int mt = blockIdx.x >> 7, kc = blockIdx.x & 127;
    const int mb = mt * 192 + (wv & 3) * 48;
    const int cbv = (wv >> 2) * 128;
    const size_t kb = (size_t)kc * 2048;

    f4v acc[3][8];
    #pragma unroll
    for (int m = 0; m < 3; ++m)
        #pragma unroll
        for (int n = 0; n < 8; ++n) { f4v z = {0, 0, 0, 0}; acc[m][n] = z; }

    for (int ks = 0; ks < 64; ++ks) {
        size_t k0 = kb + ks * 32 + lg * 8;
        h8v a[3];
        #pragma unroll
        for (int m = 0; m < 3; ++m) {
            const float* p = ml + (size_t)(mb + m * 16 + l15) * NPTS + k0;
            float4 u0 = *(const float4*)p;
            float4 u1 = *(const float4*)(p + 4);
            h8v t;
            t[0] = (_Float16)__expf(u0.x); t[1] = (_Float16)__expf(u0.y);
            t[2] = (_Float16)__expf(u0.z); t[3] = (_Float16)__expf(u0.w);
            t[4] = (_Float16)__expf(u1.x); t[5] = (_Float16)__expf(u1.y);
            t[6] = (_Float16)__expf(u1.z); t[7] = (_Float16)__expf(u1.w);
            a[m] = t;
        }
        h8v b[8];
        #pragma unroll
        for (int n = 0; n < 8; ++n)
            b[n] = *(const h8v*)(peT + (size_t)(cbv + n * 16 + l15) * NPTS + k0);
        #pragma unroll
        for (int m = 0; m < 3; ++m)
            #pragma unroll
            for (int n = 0; n < 8; ++n)
                acc[m][n] = __builtin_amdgcn_mfma_f32_16x16x32_f16(a[m], b[n], acc[m][n], 0, 0, 0);
    }
    #pragma unroll
    for (int m = 0; m < 3; ++m)
        #pragma unroll
        for (int n = 0; n < 8; ++n)
            #pragma unroll
            for (int i = 0; i < 4; ++i)
                atomicAdd(&pooled[(mb + m * 16 + lg * 4 + i) * DIM + cbv + n * 16 + l15],
                          acc[m][n][i]);
}

// ------------------------------------------------------------- finalize ----
__global__ __launch_bounds__(256) void finalize_kernel(
    const float* __restrict__ pooled, const float* __restrict__ sumexp,
    const float* __restrict__ qemb,
    const float* __restrict__ sg, const float* __restrict__ sb,
    const float* __restrict__ sw1, const float* __restrict__ sb1,
    const float* __restrict__ sw2, const float* __restrict__ sb2,
    float* __restrict__ rf, float* __restrict__ sl)
{
    __shared__ float sv[DIM], s4[4];
    const int row = blockIdx.x, g = row >> 7, d = threadIdx.x;
    float r = qemb[row * DIM + d] + pooled[row * DIM + d] / sumexp[row];
    rf[row * DIM + d] = r;
    float mean = block_sum256(r, s4) * (1.0f / DIM);
    float dv = r - mean;
    float var = block_sum256(dv * dv, s4) * (1.0f / DIM);
    float y = dv * rsqrtf(var + 1e-5f) * sg[g * DIM + d] + sb[g * DIM + d];
    sv[d] = y;
    __syncthreads();
    const float* w1 = sw1 + (size_t)g * DIM * DIM;
    float a1 = 0.0f;
    for (int k = 0; k < DIM; ++k) a1 += sv[k] * w1[k * DIM + d];
    a1 = gelu_erf(a1 + sb1[g * DIM + d]);
    float part = a1 * sw2[g * DIM + d];
    float tot = block_sum256(part, s4);
    if (d == 0) sl[row] = tot + sb2[g];
}

// ---------------------------------------------------------------- launch ---
extern "C" void kernel_launch(void* const* d_in, const int* in_sizes, int n_in,
                              void* d_out, int out_size, void* d_ws, size_t ws_size,
                              hipStream_t stream) {
    const float* pf       = (const float*)d_in[0];
    const float* ip_w1    = (const float*)d_in[1];
    const float* ip_b1    = (const float*)d_in[2];
    const float* ip_ln_g  = (const float*)d_in[3];
    const float* ip_ln_b  = (const float*)d_in[4];
    const float* ip_w2    = (const float*)d_in[5];
    const float* ip_b2    = (const float*)d_in[6];
    const float* ph_ln_g  = (const float*)d_in[7];
    const float* ph_ln_b  = (const float*)d_in[8];
    const float* ph_w1    = (const float*)d_in[9];
    const float* ph_b1    = (const float*)d_in[10];
    const float* ph_w2    = (const float*)d_in[11];
    const float* ph_b2    = (const float*)d_in[12];
    const float* qe       = (const float*)d_in[13];
    const float* qh_ln_g  = (const float*)d_in[14];
    const float* qh_ln_b  = (const float*)d_in[15];
    const float* qh_w1    = (const float*)d_in[16];
    const float* qh_b1    = (const float*)d_in[17];
    const float* qh_w2    = (const float*)d_in[18];
    const float* qh_b2    = (const float*)d_in[19];
    const float* sh_ln_g  = (const float*)d_in[20];
    const float* sh_ln_b  = (const float*)d_in[21];
    const float* sh_w1    = (const float*)d_in[22];
    const float* sh_b1    = (const float*)d_in[23];
    const float* sh_w2    = (const float*)d_in[24];
    const float* sh_b2    = (const float*)d_in[25];
    const float* lsc      = (const float*)d_in[26];

    float* out = (float*)d_out;
    float* pe_out = out;                                   // [N,256]
    float* ml     = out + 67108864LL;                      // [384,N]
    float* sl     = out + 167772160LL;                     // [384]
    float* rf     = out + 167772544LL;                     // [384,256]

    char* ws = (char*)d_ws;
    _Float16* WT1   = (_Float16*)(ws + 0);                 // [256][96]
    _Float16* WT2   = (_Float16*)(ws + 49152);             // [256][256]
    _Float16* WTp1  = (_Float16*)(ws + 180224);
    _Float16* WTp2  = (_Float16*)(ws + 311296);
    _Float16* qmask = (_Float16*)(ws + 442368);            // [384][256]
    float*    qemb  = (float*)(ws + 638976);               // [384][256]
    float*    sume  = (float*)(ws + 1032192);              // [384]
    float*    pool  = (float*)(ws + 1033728);              // [384][256]
    float*    invn  = (float*)(ws + 1426944);              // [N]
    _Float16* peT   = (_Float16*)(ws + 2475520);           // [256][N]

    prep_kernel<<<1250, 256, 0, stream>>>(ip_w1, ip_w2, ph_w1, ph_w2,
                                          WT1, WT2, WTp1, WTp2, sume, pool);
    query_kernel<<<384, 256, 0, stream>>>(qe, qh_ln_g, qh_ln_b, qh_w1, qh_b1,
                                          qh_w2, qh_b2, qemb, qmask);
    trunk_kernel<<<4096, 256, 0, stream>>>(pf, ip_b1, ip_ln_g, ip_ln_b, ip_b2,
                                           ph_ln_g, ph_ln_b, ph_b1, ph_b2,
                                           WT1, WT2, WTp1, WTp2, pe_out, invn, peT);
    logits_kernel<<<4096, 256, 0, stream>>>(qmask, pe_out, invn, lsc, ml, sume);
    pooled_kernel<<<256, 512, 0, stream>>>(ml, peT, pool);
    finalize_kernel<<<384, 256, 0, stream>>>(pool, sume, qemb, sh_ln_g, sh_ln_b,
                                             sh_w1, sh_b1, sh_w2, sh_b2, rf, sl);
}

// Round 2
// 2070.726 us; speedup vs baseline: 1.0295x; 1.0295x over previous
//
#include <hip/hip_runtime.h>
#include <math.h>

#define NPTS 262144
#define CIN  72
#define DIM  256

typedef _Float16 h8v __attribute__((ext_vector_type(8)));
typedef _Float16 h4v __attribute__((ext_vector_type(4)));
typedef float    f4v __attribute__((ext_vector_type(4)));

__device__ __forceinline__ float gelu_erf(float x) {
    return 0.5f * x * (1.0f + erff(x * 0.70710678118654752440f));
}

// ---------------------------------------------------------------- prep ----
__global__ void prep_kernel(const float* __restrict__ w1, const float* __restrict__ w2,
                            const float* __restrict__ p1, const float* __restrict__ p2,
                            _Float16* __restrict__ WT1, _Float16* __restrict__ WT2,
                            _Float16* __restrict__ WTp1, _Float16* __restrict__ WTp2,
                            float* __restrict__ sumexp, float* __restrict__ pooled)
{
    int idx = blockIdx.x * 256 + threadIdx.x;
    if (idx < 24576) {                       // WT1[n][k] = ip_w1[k][n], k padded 72->96
        int n = idx / 96, k = idx - n * 96;
        WT1[idx] = (_Float16)(k < CIN ? w1[k * DIM + n] : 0.0f);
    } else if (idx < 24576 + 65536) {
        int t = idx - 24576; int n = t >> 8, k = t & 255;
        WT2[t] = (_Float16)w2[k * DIM + n];
    } else if (idx < 24576 + 131072) {
        int t = idx - (24576 + 65536); int n = t >> 8, k = t & 255;
        WTp1[t] = (_Float16)p1[k * DIM + n];
    } else if (idx < 24576 + 196608) {
        int t = idx - (24576 + 131072); int n = t >> 8, k = t & 255;
        WTp2[t] = (_Float16)p2[k * DIM + n];
    } else if (idx < 24576 + 196608 + 384) {
        sumexp[idx - (24576 + 196608)] = 0.0f;
    } else if (idx < 24576 + 196608 + 384 + 98304) {
        pooled[idx - (24576 + 196608 + 384)] = 0.0f;
    }
}

// ----------------------------------------------------------- block reduce --
__device__ __forceinline__ float block_sum256(float v, float* s4) {
    #pragma unroll
    for (int off = 1; off < 64; off <<= 1) v += __shfl_xor(v, off, 64);
    __syncthreads();
    if ((threadIdx.x & 63) == 0) s4[threadIdx.x >> 6] = v;
    __syncthreads();
    return s4[0] + s4[1] + s4[2] + s4[3];
}

// ---------------------------------------------------------------- query ----
__global__ __launch_bounds__(256) void query_kernel(
    const float* __restrict__ qe, const float* __restrict__ qg, const float* __restrict__ qb,
    const float* __restrict__ qw1, const float* __restrict__ qb1,
    const float* __restrict__ qw2, const float* __restrict__ qb2,
    float* __restrict__ qemb, _Float16* __restrict__ qmask)
{
    __shared__ float sv[DIM], s2[DIM], s4[4];
    const int row = blockIdx.x, g = row >> 7, d = threadIdx.x;
    const float* w1 = qw1 + (size_t)g * DIM * DIM;
    const float* w2 = qw2 + (size_t)g * DIM * DIM;
    float x = qe[row * DIM + d];
    float mean = block_sum256(x, s4) * (1.0f / DIM);
    float dv = x - mean;
    float var = block_sum256(dv * dv, s4) * (1.0f / DIM);
    float y = dv * rsqrtf(var + 1e-5f) * qg[g * DIM + d] + qb[g * DIM + d];
    sv[d] = y;
    __syncthreads();
    float a1 = 0.0f;
    #pragma unroll 8
    for (int k = 0; k < DIM; ++k) a1 += sv[k] * w1[k * DIM + d];
    a1 = gelu_erf(a1 + qb1[g * DIM + d]);
    s2[d] = a1;
    __syncthreads();
    float a2 = 0.0f;
    #pragma unroll 8
    for (int k = 0; k < DIM; ++k) a2 += s2[k] * w2[k * DIM + d];
    float q2 = x + a2 + qb2[g * DIM + d];
    qemb[row * DIM + d] = q2;
    float ss = block_sum256(q2 * q2, s4);
    float inv = 1.0f / fmaxf(sqrtf(ss), 1e-12f);
    qmask[row * DIM + d] = (_Float16)(q2 * inv);
}

// ----------------------------------------------------------- trunk GEMMs ---
__device__ __forceinline__ void zero_acc44(f4v (&acc)[4][4]) {
    #pragma unroll
    for (int m = 0; m < 4; ++m)
        #pragma unroll
        for (int n = 0; n < 4; ++n) {
            f4v z = {0.0f, 0.0f, 0.0f, 0.0f};
            acc[m][n] = z;
        }
}

__device__ __forceinline__ void mm_tile(f4v (&acc)[4][4], const _Float16* sA,
                                        const _Float16* __restrict__ WT, int wtStride,
                                        int nKt, int cb, int l15, int lg)
{
    for (int kt = 0; kt < nKt; ++kt) {
        h8v a[4], b[4];
        #pragma unroll
        for (int m = 0; m < 4; ++m)
            a[m] = *(const h8v*)(sA + (m * 16 + l15) * 264 + kt * 32 + lg * 8);
        #pragma unroll
        for (int n = 0; n < 4; ++n)
            b[n] = *(const h8v*)(WT + (size_t)(cb + n * 16 + l15) * wtStride + kt * 32 + lg * 8);
        #pragma unroll
        for (int m = 0; m < 4; ++m)
            #pragma unroll
            for (int n = 0; n < 4; ++n)
                acc[m][n] = __builtin_amdgcn_mfma_f32_16x16x32_f16(a[m], b[n], acc[m][n], 0, 0, 0);
    }
}

__device__ __forceinline__ void ln_stats(const f4v (&acc)[4][4],
                                         float (*sRed)[64][2], float (*sStat)[2],
                                         int wv, int l15, int lg, int tid)
{
    #pragma unroll
    for (int m = 0; m < 4; ++m) {
        float s[4] = {0, 0, 0, 0}, ss[4] = {0, 0, 0, 0};
        #pragma unroll
        for (int n = 0; n < 4; ++n)
            #pragma unroll
            for (int i = 0; i < 4; ++i) { float v = acc[m][n][i]; s[i] += v; ss[i] += v * v; }
        #pragma unroll
        for (int off = 1; off < 16; off <<= 1)
            #pragma unroll
            for (int i = 0; i < 4; ++i) {
                s[i] += __shfl_xor(s[i], off, 64);
                ss[i] += __shfl_xor(ss[i], off, 64);
            }
        if (l15 == 0)
            #pragma unroll
            for (int i = 0; i < 4; ++i) {
                int r = m * 16 + lg * 4 + i;
                sRed[wv][r][0] = s[i]; sRed[wv][r][1] = ss[i];
            }
    }
    __syncthreads();
    if (tid < 64) {
        float s = 0, ss = 0;
        #pragma unroll
        for (int w = 0; w < 4; ++w) { s += sRed[w][tid][0]; ss += sRed[w][tid][1]; }
        float mean = s * (1.0f / 256.0f);
        float var = ss * (1.0f / 256.0f) - mean * mean;
        sStat[tid][0] = mean;
        sStat[tid][1] = rsqrtf(var + 1e-5f);
    }
    __syncthreads();
}

__global__ __launch_bounds__(256, 4) void trunk_kernel(
    const float* __restrict__ pf,
    const float* __restrict__ ib1, const float* __restrict__ ig, const float* __restrict__ ibb,
    const float* __restrict__ ib2,
    const float* __restrict__ pg, const float* __restrict__ pb,
    const float* __restrict__ pb1, const float* __restrict__ pb2,
    const _Float16* __restrict__ WT1, const _Float16* __restrict__ WT2,
    const _Float16* __restrict__ WTp1, const _Float16* __restrict__ WTp2,
    float* __restrict__ peo, float* __restrict__ inv_norm, _Float16* __restrict__ peT,
    _Float16* __restrict__ pmH)
{
    __shared__ __align__(16) _Float16 sAct[64][264];
    __shared__ float sRed[4][64][2];
    __shared__ float sStat[64][2];

    const int tid = threadIdx.x;
    const int wv = tid >> 6, ln = tid & 63, l15 = ln & 15, lg = ln >> 4;
    const int cb = wv * 64;
    const int rowbase = blockIdx.x * 64;

    // stage point_feat 64x72 (vectorized) + zero pad to 96
    for (int idx = tid; idx < 1152; idx += 256) {
        int r = idx / 18, c4 = idx - r * 18;
        float4 u = *(const float4*)(pf + (size_t)(rowbase + r) * CIN + c4 * 4);
        h4v h; h[0] = (_Float16)u.x; h[1] = (_Float16)u.y; h[2] = (_Float16)u.z; h[3] = (_Float16)u.w;
        *(h4v*)(&sAct[r][c4 * 4]) = h;
    }
    for (int idx = tid; idx < 384; idx += 256) {
        int r = idx / 6, c4 = idx - r * 6;
        h4v z = {};
        *(h4v*)(&sAct[r][72 + c4 * 4]) = z;
    }
    __syncthreads();

    f4v acc[4][4];
    h4v h16[4][4];     // fp16-packed residual h

    // ---- GEMM1: pf @ ip_w1, +b1, LN, GELU -> act1
    zero_acc44(acc);
    mm_tile(acc, &sAct[0][0], WT1, 96, 3, cb, l15, lg);
    {
        float bc[4], gc[4], bb[4];
        #pragma unroll
        for (int n = 0; n < 4; ++n) {
            int col = cb + n * 16 + l15;
            bc[n] = ib1[col]; gc[n] = ig[col]; bb[n] = ibb[col];
        }
        #pragma unroll
        for (int m = 0; m < 4; ++m)
            #pragma unroll
            for (int n = 0; n < 4; ++n)
                #pragma unroll
                for (int i = 0; i < 4; ++i) acc[m][n][i] += bc[n];
        ln_stats(acc, sRed, sStat, wv, l15, lg, tid);
        #pragma unroll
        for (int m = 0; m < 4; ++m)
            #pragma unroll
            for (int i = 0; i < 4; ++i) {
                int r = m * 16 + lg * 4 + i;
                float mean = sStat[r][0], rstd = sStat[r][1];
                #pragma unroll
                for (int n = 0; n < 4; ++n) {
                    float v = (acc[m][n][i] - mean) * rstd * gc[n] + bb[n];
                    sAct[r][cb + n * 16 + l15] = (_Float16)gelu_erf(v);
                }
            }
    }
    __syncthreads();

    // ---- GEMM2: act1 @ ip_w2, +b2 = h ; act2 = LN(h)
    zero_acc44(acc);
    mm_tile(acc, &sAct[0][0], WT2, 256, 8, cb, l15, lg);
    {
        float bc[4], gc[4], bb[4];
        #pragma unroll
        for (int n = 0; n < 4; ++n) {
            int col = cb + n * 16 + l15;
            bc[n] = ib2[col]; gc[n] = pg[col]; bb[n] = pb[col];
        }
        #pragma unroll
        for (int m = 0; m < 4; ++m)
            #pragma unroll
            for (int n = 0; n < 4; ++n)
                #pragma unroll
                for (int i = 0; i < 4; ++i) {
                    float h = acc[m][n][i] + bc[n];
                    acc[m][n][i] = h;
                    h16[m][n][i] = (_Float16)h;     // keep residual in fp16
                }
        ln_stats(acc, sRed, sStat, wv, l15, lg, tid);
        #pragma unroll
        for (int m = 0; m < 4; ++m)
            #pragma unroll
            for (int i = 0; i < 4; ++i) {
                int r = m * 16 + lg * 4 + i;
                float mean = sStat[r][0], rstd = sStat[r][1];
                #pragma unroll
                for (int n = 0; n < 4; ++n) {
                    float v = (acc[m][n][i] - mean) * rstd * gc[n] + bb[n];
                    sAct[r][cb + n * 16 + l15] = (_Float16)v;
                }
            }
    }
    __syncthreads();

    // ---- GEMM3: act2 @ ph_w1, +b, GELU -> act3
    zero_acc44(acc);
    mm_tile(acc, &sAct[0][0], WTp1, 256, 8, cb, l15, lg);
    __syncthreads();
    {
        float bc[4];
        #pragma unroll
        for (int n = 0; n < 4; ++n) bc[n] = pb1[cb + n * 16 + l15];
        #pragma unroll
        for (int m = 0; m < 4; ++m)
            #pragma unroll
            for (int i = 0; i < 4; ++i) {
                int r = m * 16 + lg * 4 + i;
                #pragma unroll
                for (int n = 0; n < 4; ++n) {
                    float v = gelu_erf(acc[m][n][i] + bc[n]);
                    sAct[r][cb + n * 16 + l15] = (_Float16)v;
                }
            }
    }
    __syncthreads();

    // ---- GEMM4: act3 @ ph_w2, +b, +h  -> point_embed
    zero_acc44(acc);
    mm_tile(acc, &sAct[0][0], WTp2, 256, 8, cb, l15, lg);
    {
        float bc[4];
        #pragma unroll
        for (int n = 0; n < 4; ++n) bc[n] = pb2[cb + n * 16 + l15];
        #pragma unroll
        for (int m = 0; m < 4; ++m)
            #pragma unroll
            for (int n = 0; n < 4; ++n)
                #pragma unroll
                for (int i = 0; i < 4; ++i)
                    acc[m][n][i] += bc[n] + (float)h16[m][n][i];
        // row L2-norm
        #pragma unroll
        for (int m = 0; m < 4; ++m) {
            float ss[4] = {0, 0, 0, 0};
            #pragma unroll
            for (int n = 0; n < 4; ++n)
                #pragma unroll
                for (int i = 0; i < 4; ++i) { float v = acc[m][n][i]; ss[i] += v * v; }
            #pragma unroll
            for (int off = 1; off < 16; off <<= 1)
                #pragma unroll
                for (int i = 0; i < 4; ++i) ss[i] += __shfl_xor(ss[i], off, 64);
            if (l15 == 0)
                #pragma unroll
                for (int i = 0; i < 4; ++i) sRed[wv][m * 16 + lg * 4 + i][0] = ss[i];
        }
        __syncthreads();
        if (tid < 64) {
            float ss = 0;
            #pragma unroll
            for (int w = 0; w < 4; ++w) ss += sRed[w][tid][0];
            float inv = 1.0f / fmaxf(sqrtf(ss), 1e-12f);
            sStat[tid][0] = inv;
            inv_norm[rowbase + tid] = inv;
        }
        __syncthreads();
        #pragma unroll
        for (int m = 0; m < 4; ++m)
            #pragma unroll
            for (int n = 0; n < 4; ++n) {
                int col = cb + n * 16 + l15;
                h4v pk;
                #pragma unroll
                for (int i = 0; i < 4; ++i) {
                    int r = m * 16 + lg * 4 + i;
                    float v = acc[m][n][i];
                    peo[(size_t)(rowbase + r) * DIM + col] = v;
                    if (pmH) pmH[(size_t)(rowbase + r) * DIM + col] = (_Float16)(v * sStat[r][0]);
                    pk[i] = (_Float16)v;
                }
                *(h4v*)(peT + (size_t)col * NPTS + rowbase + m * 16 + lg * 4) = pk;
            }
    }
}

// --------------------------------------------------------------- logits ----
template<bool PM>
__global__ __launch_bounds__(256, 2) void logits_kernel(
    const _Float16* __restrict__ qmask, const _Float16* __restrict__ pmH,
    const float* __restrict__ peo, const float* __restrict__ inv_norm,
    const float* __restrict__ lsc,
    float* __restrict__ ml, float* __restrict__ sumexp)
{
    const int tid = threadIdx.x;
    const int wv = tid >> 6, ln = tid & 63, l15 = ln & 15, lg = ln >> 4;
    const int nb = blockIdx.x * 64;
    const int mb = wv * 96;

    f4v acc[6][4];
    #pragma unroll
    for (int m = 0; m < 6; ++m)
        #pragma unroll
        for (int n = 0; n < 4; ++n) { f4v z = {0, 0, 0, 0}; acc[m][n] = z; }

    float inv[4];
    if constexpr (!PM) {
        #pragma unroll
        for (int n = 0; n < 4; ++n) inv[n] = inv_norm[nb + n * 16 + l15];
    }

    auto loadB = [&](int kt, h8v (&b)[4]) {
        #pragma unroll
        for (int n = 0; n < 4; ++n) {
            if constexpr (PM) {
                b[n] = *(const h8v*)(pmH + (size_t)(nb + n * 16 + l15) * DIM + kt * 32 + lg * 8);
            } else {
                const float* p = peo + (size_t)(nb + n * 16 + l15) * DIM + kt * 32 + lg * 8;
                float4 u0 = *(const float4*)p;
                float4 u1 = *(const float4*)(p + 4);
                h8v t;
                t[0] = (_Float16)(u0.x * inv[n]); t[1] = (_Float16)(u0.y * inv[n]);
                t[2] = (_Float16)(u0.z * inv[n]); t[3] = (_Float16)(u0.w * inv[n]);
                t[4] = (_Float16)(u1.x * inv[n]); t[5] = (_Float16)(u1.y * inv[n]);
                t[6] = (_Float16)(u1.z * inv[n]); t[7] = (_Float16)(u1.w * inv[n]);
                b[n] = t;
            }
        }
    };

    h8v b0[4];
    loadB(0, b0);
    #pragma unroll
    for (int kt = 0; kt < 8; ++kt) {
        h8v b1[4];
        if (kt < 7) loadB(kt + 1, b1);
        h8v a[6];
        #pragma unroll
        for (int m = 0; m < 6; ++m)
            a[m] = *(const h8v*)(qmask + (size_t)(mb + m * 16 + l15) * DIM + kt * 32 + lg * 8);
        #pragma unroll
        for (int m = 0; m < 6; ++m)
            #pragma unroll
            for (int n = 0; n < 4; ++n)
                acc[m][n] = __builtin_amdgcn_mfma_f32_16x16x32_f16(a[m], b0[n], acc[m][n], 0, 0, 0);
        if (kt < 7) {
            #pragma unroll
            for (int n = 0; n < 4; ++n) b0[n] = b1[n];
        }
    }

    #pragma unroll
    for (int m = 0; m < 6; ++m) {
        int g = (mb + m * 16) >> 7;
        float sc = expf(lsc[g]);
        float es[4] = {0, 0, 0, 0};
        #pragma unroll
        for (int n = 0; n < 4; ++n)
            #pragma unroll
            for (int i = 0; i < 4; ++i) {
                int row = mb + m * 16 + lg * 4 + i;
                int col = nb + n * 16 + l15;
                float v = acc[m][n][i] * sc;
                ml[(size_t)row * NPTS + col] = v;
                es[i] += __expf(v);
            }
        #pragma unroll
        for (int off = 1; off < 16; off <<= 1)
            #pragma unroll
            for (int i = 0; i < 4; ++i) es[i] += __shfl_xor(es[i], off, 64);
        if (l15 == 0)
            #pragma unroll
            for (int i = 0; i < 4; ++i)
                atomicAdd(&sumexp[mb + m * 16 + lg * 4 + i], es[i]);
    }
}

// --------------------------------------------------------------- pooled ----
__global__ __launch_bounds__(512, 2) void pooled_kernel(
    const float* __restrict__ ml, const _Float16* __restrict__ peT,
    float* __restrict__ pooled)
{
    const int tid = threadIdx.x;
    const int wv = tid >> 6, ln = tid & 63, l15 = ln & 15, lg = ln >> 4;
    const int qs = blockIdx.x >> 8, kc = blockIdx.x & 255;
    const int rb = qs * 192 + (wv & 3) * 48;        // 48-row q slab per wave
    const int db = (wv >> 2) * 128;                 // 128-col d half per wave
    const size_t kb = (size_t)kc * 1024;

    f4v acc[3][8];
    #pragma unroll
    for (int m = 0; m < 3; ++m)
        #pragma unroll
        for (int n = 0; n < 8; ++n) { f4v z = {0, 0, 0, 0}; acc[m][n] = z; }

    auto loadA = [&](int ks, f4v (&a)[6]) {
        #pragma unroll
        for (int m = 0; m < 3; ++m) {
            const float* p = ml + (size_t)(rb + m * 16 + l15) * NPTS + kb + ks * 32 + lg * 8;
            a[2 * m]     = *(const f4v*)p;
            a[2 * m + 1] = *(const f4v*)(p + 4);
        }
    };
    auto loadB = [&](int ks, h8v (&b)[8]) {
        #pragma unroll
        for (int n = 0; n < 8; ++n)
            b[n] = *(const h8v*)(peT + (size_t)(db + n * 16 + l15) * NPTS + kb + ks * 32 + lg * 8);
    };

    f4v a0[6]; h8v b0[8];
    loadA(0, a0); loadB(0, b0);
    for (int ks = 0; ks < 32; ++ks) {
        f4v a1[6]; h8v b1[8];
        if (ks < 31) { loadA(ks + 1, a1); loadB(ks + 1, b1); }
        h8v pa[3];
        #pragma unroll
        for (int m = 0; m < 3; ++m) {
            h8v t;
            #pragma unroll
            for (int j = 0; j < 4; ++j) {
                t[j]     = (_Float16)__expf(a0[2 * m][j]);
                t[4 + j] = (_Float16)__expf(a0[2 * m + 1][j]);
            }
            pa[m] = t;
        }
        #pragma unroll
        for (int m = 0; m < 3; ++m)
            #pragma unroll
            for (int n = 0; n < 8; ++n)
                acc[m][n] = __builtin_amdgcn_mfma_f32_16x16x32_f16(pa[m], b0[n], acc[m][n], 0, 0, 0);
        if (ks < 31) {
            #pragma unroll
            for (int i = 0; i < 6; ++i) a0[i] = a1[i];
            #pragma unroll
            for (int n = 0; n < 8; ++n) b0[n] = b1[n];
        }
    }
    #pragma unroll
    for (int m = 0; m < 3; ++m)
        #pragma unroll
        for (int n = 0; n < 8; ++n)
            #pragma unroll
            for (int i = 0; i < 4; ++i)
                atomicAdd(&pooled[(size_t)(rb + m * 16 + lg * 4 + i) * DIM + db + n * 16 + l15],
                          acc[m][n][i]);
}

// ------------------------------------------------------------- finalize ----
__global__ __launch_bounds__(256) void finalize_kernel(
    const float* __restrict__ pooled, const float* __restrict__ sumexp,
    const float* __restrict__ qemb,
    const float* __restrict__ sg, const float* __restrict__ sb,
    const float* __restrict__ sw1, const float* __restrict__ sb1,
    const float* __restrict__ sw2, const float* __restrict__ sb2,
    float* __restrict__ rf, float* __restrict__ sl)
{
    __shared__ float sv[DIM], s4[4];
    const int row = blockIdx.x, g = row >> 7, d = threadIdx.x;
    float r = qemb[row * DIM + d] + pooled[row * DIM + d] / sumexp[row];
    rf[row * DIM + d] = r;
    float mean = block_sum256(r, s4) * (1.0f / DIM);
    float dv = r - mean;
    float var = block_sum256(dv * dv, s4) * (1.0f / DIM);
    float y = dv * rsqrtf(var + 1e-5f) * sg[g * DIM + d] + sb[g * DIM + d];
    sv[d] = y;
    __syncthreads();
    const float* w1 = sw1 + (size_t)g * DIM * DIM;
    float a1 = 0.0f;
    #pragma unroll 8
    for (int k = 0; k < DIM; ++k) a1 += sv[k] * w1[k * DIM + d];
    a1 = gelu_erf(a1 + sb1[g * DIM + d]);
    float part = a1 * sw2[g * DIM + d];
    float tot = block_sum256(part, s4);
    if (d == 0) sl[row] = tot + sb2[g];
}

// ---------------------------------------------------------------- launch ---
extern "C" void kernel_launch(void* const* d_in, const int* in_sizes, int n_in,
                              void* d_out, int out_size, void* d_ws, size_t ws_size,
                              hipStream_t stream) {
    const float* pf       = (const float*)d_in[0];
    const float* ip_w1    = (const float*)d_in[1];
    const float* ip_b1    = (const float*)d_in[2];
    const float* ip_ln_g  = (const float*)d_in[3];
    const float* ip_ln_b  = (const float*)d_in[4];
    const float* ip_w2    = (const float*)d_in[5];
    const float* ip_b2    = (const float*)d_in[6];
    const float* ph_ln_g  = (const float*)d_in[7];
    const float* ph_ln_b  = (const float*)d_in[8];
    const float* ph_w1    = (const float*)d_in[9];
    const float* ph_b1    = (const float*)d_in[10];
    const float* ph_w2    = (const float*)d_in[11];
    const float* ph_b2    = (const float*)d_in[12];
    const float* qe       = (const float*)d_in[13];
    const float* qh_ln_g  = (const float*)d_in[14];
    const float* qh_ln_b  = (const float*)d_in[15];
    const float* qh_w1    = (const float*)d_in[16];
    const float* qh_b1    = (const float*)d_in[17];
    const float* qh_w2    = (const float*)d_in[18];
    const float* qh_b2    = (const float*)d_in[19];
    const float* sh_ln_g  = (const float*)d_in[20];
    const float* sh_ln_b  = (const float*)d_in[21];
    const float* sh_w1    = (const float*)d_in[22];
    const float* sh_b1    = (const float*)d_in[23];
    const float* sh_w2    = (const float*)d_in[24];
    const float* sh_b2    = (const float*)d_in[25];
    const float* lsc      = (const float*)d_in[26];

    float* out = (float*)d_out;
    float* pe_out = out;                                   // [N,256]
    float* ml     = out + 67108864LL;                      // [384,N]
    float* sl     = out + 167772160LL;                     // [384]
    float* rf     = out + 167772544LL;                     // [384,256]

    char* ws = (char*)d_ws;
    _Float16* WT1   = (_Float16*)(ws + 0);                 // [256][96]
    _Float16* WT2   = (_Float16*)(ws + 49152);             // [256][256]
    _Float16* WTp1  = (_Float16*)(ws + 180224);
    _Float16* WTp2  = (_Float16*)(ws + 311296);
    _Float16* qmask = (_Float16*)(ws + 442368);            // [384][256]
    float*    qemb  = (float*)(ws + 638976);               // [384][256]
    float*    sume  = (float*)(ws + 1032192);              // [384]
    float*    pool  = (float*)(ws + 1033728);              // [384][256]
    float*    invn  = (float*)(ws + 1426944);              // [N]

    const size_t PM_BYTES = 134217728ULL;                  // [N][256] fp16
    bool big = ws_size >= (2475520ULL + 2 * PM_BYTES);
    _Float16* pmH = big ? (_Float16*)(ws + 2475520) : (_Float16*)nullptr;
    _Float16* peT = big ? (_Float16*)(ws + 2475520 + PM_BYTES)
                        : (_Float16*)(ws + 2475520);       // [256][N]

    prep_kernel<<<1250, 256, 0, stream>>>(ip_w1, ip_w2, ph_w1, ph_w2,
                                          WT1, WT2, WTp1, WTp2, sume, pool);
    query_kernel<<<384, 256, 0, stream>>>(qe, qh_ln_g, qh_ln_b, qh_w1, qh_b1,
                                          qh_w2, qh_b2, qemb, qmask);
    trunk_kernel<<<4096, 256, 0, stream>>>(pf, ip_b1, ip_ln_g, ip_ln_b, ip_b2,
                                           ph_ln_g, ph_ln_b, ph_b1, ph_b2,
                                           WT1, WT2, WTp1, WTp2, pe_out, invn, peT, pmH);
    if (big)
        logits_kernel<true><<<4096, 256, 0, stream>>>(qmask, pmH, pe_out, invn, lsc, ml, sume);
    else
        logits_kernel<false><<<4096, 256, 0, stream>>>(qmask, pmH, pe_out, invn, lsc, ml, sume);
    pooled_kernel<<<512, 512, 0, stream>>>(ml, peT, pool);
    finalize_kernel<<<384, 256, 0, stream>>>(pool, sume, qemb, sh_ln_g, sh_ln_b,
                                             sh_w1, sh_b1, sh_w2, sh_b2, rf, sl);
}